// Round 1
// baseline (189.799 us; speedup 1.0000x reference)
//
#include <hip/hip_runtime.h>

#define KBINS 256
#define NPB (512 * 512)   // elements per batch = 262144
#define BATCHES 8
#define BLOCKS_PER_BATCH 64
#define BLOCK_THREADS 256

// d_out is poisoned 0xAA before every launch -> explicit zero-init kernel.
__global__ void zero_out_kernel(float* __restrict__ out) {
    int i = blockIdx.x * blockDim.x + threadIdx.x;
    if (i < BATCHES * KBINS) out[i] = 0.0f;
}

// Soft histogram: out[b,k] = (1/N) * sum_n sigmoid((x-mu_k+L/2)/W) - sigmoid((x-mu_k-L/2)/W)
// With t = x*K - (k+0.5):  pj = sigmoid(2.5t+1.25) - sigmoid(2.5t-1.25)
//                              = 1/(1+E*e^-1.25) - 1/(1+E*e^+1.25),  E = e^{-2.5t}
// pj < 2.9e-7 for |t| >= 6.5 -> window of 13 bins around j = floor(x*K);
// summed truncation error per bin < ~3e-4 / N ~ 1e-9, far under the 8.4e-5 threshold.
__launch_bounds__(BLOCK_THREADS)
__global__ void hist_kernel(const float* __restrict__ x, float* __restrict__ out) {
    __shared__ float sh[KBINS];
    const int tid = threadIdx.x;
    for (int i = tid; i < KBINS; i += BLOCK_THREADS) sh[i] = 0.0f;
    __syncthreads();

    const int b = blockIdx.y;
    const float4* __restrict__ xb = (const float4*)(x + (size_t)b * NPB);
    const int nvec = NPB / 4;  // 65536 float4 per batch

    const float c1 = 0.2865047968601901f;   // e^-1.25
    const float c2 = 3.4903429574618414f;   // e^+1.25
    const float S  = 12.182493960703473f;   // e^+2.5 (E growth per bin step)

    for (int i = blockIdx.x * BLOCK_THREADS + tid; i < nvec;
         i += BLOCKS_PER_BATCH * BLOCK_THREADS) {
        float4 v4 = xb[i];
        float vv[4] = {v4.x, v4.y, v4.z, v4.w};
        #pragma unroll
        for (int c = 0; c < 4; ++c) {
            float t0 = vv[c] * 256.0f;        // x in [0,1) -> t0 in [0,256)
            int j = (int)t0;                  // owning bin
            float f = t0 - (float)j;          // frac in [0,1)
            // E at dk=-6: t = t0-(j-6+0.5) = f+5.5 -> E = e^{-2.5(f+5.5)}
            float E = __expf(-2.5f * (f + 5.5f));
            #pragma unroll
            for (int dk = -6; dk <= 6; ++dk) {
                int k = j + dk;
                float p = __builtin_amdgcn_rcpf(fmaf(E, c1, 1.0f))
                        - __builtin_amdgcn_rcpf(fmaf(E, c2, 1.0f));
                E *= S;
                if (k >= 0 && k < KBINS) atomicAdd(&sh[k], p);
            }
        }
    }

    __syncthreads();
    const float inv_n = 1.0f / (float)NPB;
    for (int i = tid; i < KBINS; i += BLOCK_THREADS) {
        atomicAdd(&out[b * KBINS + i], sh[i] * inv_n);
    }
}

extern "C" void kernel_launch(void* const* d_in, const int* in_sizes, int n_in,
                              void* d_out, int out_size, void* d_ws, size_t ws_size,
                              hipStream_t stream) {
    const float* x = (const float*)d_in[0];
    float* out = (float*)d_out;

    zero_out_kernel<<<(BATCHES * KBINS + 255) / 256, 256, 0, stream>>>(out);

    dim3 grid(BLOCKS_PER_BATCH, BATCHES);
    hist_kernel<<<grid, BLOCK_THREADS, 0, stream>>>(x, out);
}

// Round 2
// 86.587 us; speedup vs baseline: 2.1920x; 2.1920x over previous
//
#include <hip/hip_runtime.h>

#define KBINS 256
#define NPB (512 * 512)     // elements per batch = 262144
#define BATCHES 8
#define WPB 64              // one-wave blocks per batch
#define WAVE 64
#define STRIDE (WPB * WAVE) // 4096 float4 per sweep per batch
#define F4_PER_LANE 16      // 65536 float4 / 4096
#define WIN 5
#define NBIN 11
#define SH_MASK (KBINS * WAVE - 1)

// d_out poisoned 0xAA before every launch -> explicit zero-init.
__global__ void zero_out_kernel(float* __restrict__ out) {
    int i = blockIdx.x * blockDim.x + threadIdx.x;
    if (i < BATCHES * KBINS) out[i] = 0.0f;
}

// pj(t) = sigmoid(2.5t+1.25) - sigmoid(2.5t-1.25), t = x*K - (k+0.5)
//       = knum*E / (1 + ssum*E + E^2),  E = e^{-2.5t}   (since e^{1.25}*e^{-1.25}=1)
// window +-5 bins: dropped mass <= 3.2*e^{-2.5*5.5} ~ 3.4e-6 per side, << 8.4e-5.
//
// LDS: sh[bin][col], col = lane -> each lane owns a column; no atomics, no races.
// bank = lane%32 -> 2-way aliasing only (free). 64 KiB/block, 2 blocks/CU.
__launch_bounds__(WAVE)
__global__ void hist_kernel(const float* __restrict__ x, float* __restrict__ out) {
    __shared__ float sh[KBINS * WAVE];   // 64 KiB
    const int lane = threadIdx.x;
    const int b = blockIdx.y;

    // zero LDS: 4096 float4, 64 per lane
    float4* sh4 = (float4*)sh;
    for (int i = lane; i < KBINS * WAVE / 4; i += WAVE)
        sh4[i] = make_float4(0.f, 0.f, 0.f, 0.f);
    __syncthreads();

    const float4* __restrict__ xb = (const float4*)(x + (size_t)b * NPB);
    const float knum = 3.20383816f;   // e^1.25 - e^-1.25
    const float ssum = 3.77684775f;   // e^1.25 + e^-1.25
    const float S    = 12.1824940f;   // e^2.5 (E growth per bin step)

    const int base = blockIdx.x * WAVE + lane;
    float4 cur = xb[base];
    for (int it = 0; it < F4_PER_LANE; ++it) {
        float4 nxt = cur;
        if (it + 1 < F4_PER_LANE) nxt = xb[base + (it + 1) * STRIDE];  // prefetch
        float vv[4] = {cur.x, cur.y, cur.z, cur.w};
        #pragma unroll
        for (int c = 0; c < 4; ++c) {
            float t0 = vv[c] * 256.0f;        // t0 in [0,256)
            int j = (int)t0;
            float f = t0 - (float)j;          // frac in [0,1)
            // E at dk=-5: t = f + 4.5
            float E = __expf(fmaf(f, -2.5f, -11.25f));
            float pv[NBIN];
            #pragma unroll
            for (int u = 0; u < NBIN; ++u) {
                float denom = fmaf(E, E, fmaf(ssum, E, 1.0f));
                float p = knum * E * __builtin_amdgcn_rcpf(denom);
                // out-of-range bin: zero the contribution, wrapped address is harmless
                pv[u] = ((unsigned)(j + u - WIN) < (unsigned)KBINS) ? p : 0.0f;
                E *= S;
            }
            // batched RMW: 11 independent reads -> one wait -> adds -> 11 writes.
            // Same-wave DS ops are in-order: inter-element RAW on overlapping
            // windows is safe. Address wrap via two's-complement & SH_MASK.
            const int abase = ((j - WIN) << 6) + lane;
            float tv[NBIN];
            #pragma unroll
            for (int u = 0; u < NBIN; ++u)
                tv[u] = sh[(abase + (u << 6)) & SH_MASK];
            #pragma unroll
            for (int u = 0; u < NBIN; ++u)
                sh[(abase + (u << 6)) & SH_MASK] = tv[u] + pv[u];
        }
        cur = nxt;
    }
    __syncthreads();

    // reduce 64 columns per bin; rotation (lane+i)&63 keeps banks conflict-free
    const float inv_n = 1.0f / (float)NPB;
    #pragma unroll
    for (int g = 0; g < 4; ++g) {
        int k = g * WAVE + lane;
        const float* row = sh + (k << 6);
        float a0 = 0.f, a1 = 0.f, a2 = 0.f, a3 = 0.f;
        #pragma unroll 4
        for (int i = 0; i < WAVE; i += 4) {
            a0 += row[(lane + i)     & (WAVE - 1)];
            a1 += row[(lane + i + 1) & (WAVE - 1)];
            a2 += row[(lane + i + 2) & (WAVE - 1)];
            a3 += row[(lane + i + 3) & (WAVE - 1)];
        }
        atomicAdd(&out[b * KBINS + k], ((a0 + a1) + (a2 + a3)) * inv_n);
    }
}

extern "C" void kernel_launch(void* const* d_in, const int* in_sizes, int n_in,
                              void* d_out, int out_size, void* d_ws, size_t ws_size,
                              hipStream_t stream) {
    const float* x = (const float*)d_in[0];
    float* out = (float*)d_out;

    zero_out_kernel<<<(BATCHES * KBINS + 255) / 256, 256, 0, stream>>>(out);

    dim3 grid(WPB, BATCHES);
    hist_kernel<<<grid, WAVE, 0, stream>>>(x, out);
}